// Round 15
// baseline (188.149 us; speedup 1.0000x reference)
//
#include <hip/hip_runtime.h>

// YOLO v1-style loss, forward only.
// prediction: [32768, 7, 7, 12] f32   (B=2 boxes * 5 + C=2 classes)
// target:     [32768, 7, 7, 7]  f32   (x,y,w,h,obj, c0,c1)
// output:     scalar f32
//
// Round-14 (resubmit; prior attempt hit GPU-acquisition timeout):
// wave-autonomous coalesced staging.
//   Every global load is lane-contiguous float4 (1 KB/wave-instr, ~8 cache
//   lines) instead of the 192 B lane-stride scatter (~56 lines) that pinned
//   rounds 2-13 at ~46 us. Per 64-cell tile: 3 pred + 2 targ coalesced loads
//   -> ds_write linear (conflict-free) -> ds_read per-cell (b128 x3 stride
//   48 B = 2-way, ~free; targ b32 x7 stride 28 B, gcd(7,32)=1 conflict-free).
//   NO __syncthreads anywhere: each wave reads only its own LDS region, so
//   ordering is purely waitcnt-based (no block-wide barrier drain).
//   Double-buffered in registers AND LDS; 4 tiles/wave fully unrolled, next
//   tile's 5 loads in flight under current tile's compute.

constexpr int S = 7;
constexpr int CELLS = 32768 * S * S;       // 1,605,632
constexpr int TPB = 256;                   // 4 waves/block
constexpr int WPB = TPB / 64;              // 4
constexpr int TILES = CELLS / 64;          // 25,088 tiles of 64 cells
constexpr int TPW = 4;                     // tiles per wave
constexpr int NWAVES = TILES / TPW;        // 6,272
constexpr int NBLK = NWAVES / WPB;         // 1,568
constexpr float LAMBDA_COORD = 5.0f;
constexpr float LAMBDA_NOOBJ = 0.5f;
constexpr float INV_S = 1.0f / 7.0f;

constexpr int SLOT = 304;                  // float4 slots per wave-buffer: 192 pred + 112 targ

__device__ __forceinline__ float cell_loss(const float* p, const float* t,
                                           float fcol, float frow) {
    float x0 = p[0], y0 = p[1], w0 = p[2], h0 = p[3], c0 = p[4];
    float x1 = p[5], y1 = p[6], w1 = p[7], h1 = p[8], c1 = p[9];
    float q0 = p[10], q1 = p[11];
    float tx = t[0], ty = t[1], tw = t[2], th = t[3], tp = t[4];
    float s0 = t[5], s1 = t[6];

    float tcx = (tx + fcol) * INV_S, tcy = (ty + frow) * INV_S;
    float tX1 = tcx - tw * 0.5f, tY1 = tcy - th * 0.5f;
    float tX2 = tcx + tw * 0.5f, tY2 = tcy + th * 0.5f;
    float ta = fabsf((tX2 - tX1) * (tY2 - tY1));

    float cx0 = (x0 + fcol) * INV_S, cy0 = (y0 + frow) * INV_S;
    float aX1 = cx0 - w0 * 0.5f, aY1 = cy0 - h0 * 0.5f;
    float aX2 = cx0 + w0 * 0.5f, aY2 = cy0 + h0 * 0.5f;
    float inter0 = fmaxf(fminf(aX2, tX2) - fmaxf(aX1, tX1), 0.0f) *
                   fmaxf(fminf(aY2, tY2) - fmaxf(aY1, tY1), 0.0f);
    float ar0 = fabsf((aX2 - aX1) * (aY2 - aY1));
    float u0 = ar0 + ta - inter0 + 1e-8f;      // > 0 always

    float cx1 = (x1 + fcol) * INV_S, cy1 = (y1 + frow) * INV_S;
    float bX1 = cx1 - w1 * 0.5f, bY1 = cy1 - h1 * 0.5f;
    float bX2 = cx1 + w1 * 0.5f, bY2 = cy1 + h1 * 0.5f;
    float inter1 = fmaxf(fminf(bX2, tX2) - fmaxf(bX1, tX1), 0.0f) *
                   fmaxf(fminf(bY2, tY2) - fmaxf(bY1, tY1), 0.0f);
    float ar1 = fabsf((bX2 - bX1) * (bY2 - bY1));
    float u1 = ar1 + ta - inter1 + 1e-8f;

    // argmax(iou): box1 iff iou1 > iou0  <=>  inter1*u0 > inter0*u1  (u > 0)
    bool sel1 = inter1 * u0 > inter0 * u1;
    float px = sel1 ? x1 : x0;
    float py = sel1 ? y1 : y0;
    float pw = sel1 ? w1 : w0;
    float ph = sel1 ? h1 : h0;
    float pp = sel1 ? c1 : c0;

    float obj = (tp > 0.0f) ? 1.0f : 0.0f;
    float noobj = 1.0f - obj;

    float dx = px - tx, dy = py - ty;
    float centre = dx * dx + dy * dy;

    float sgnw = (pw > 0.0f) ? 1.0f : ((pw < 0.0f) ? -1.0f : 0.0f);
    float sgnh = (ph > 0.0f) ? 1.0f : ((ph < 0.0f) ? -1.0f : 0.0f);
    float dw = sgnw * sqrtf(fabsf(pw) + 1e-6f) - sqrtf(tw);
    float dh = sgnh * sqrtf(fabsf(ph) + 1e-6f) - sqrtf(th);
    float dim = dw * dw + dh * dh;

    float dconf = pp - tp;
    float n0 = c0 - tp, n1 = c1 - tp;
    float dc0 = q0 - s0, dc1 = q1 - s1;

    return obj * (LAMBDA_COORD * (centre + dim) + dconf * dconf + dc0 * dc0 + dc1 * dc1)
         + noobj * LAMBDA_NOOBJ * (n0 * n0 + n1 * n1);
}

__global__ __launch_bounds__(TPB)
void yolo_loss_kernel(const float* __restrict__ pred,
                      const float* __restrict__ targ,
                      double* __restrict__ ws) {
    __shared__ float4 lds[WPB][2][SLOT];   // 38,912 B

    const int wid = threadIdx.x >> 6;
    const int L   = threadIdx.x & 63;
    const int gw  = blockIdx.x * WPB + wid;    // global wave id, 0..6271
    const int tile0 = gw * TPW;

    float acc = 0.0f;
    float4 A[5], B[5];

    // coalesced tile load: 3 pred float4-instr + 2 targ float4-instr (1 KB each)
    auto LOADG = [&](float4* r, int t) {
        const float4* pb = reinterpret_cast<const float4*>(pred) + (size_t)t * 192;
        const float4* tb = reinterpret_cast<const float4*>(targ) + (size_t)t * 112;
        r[0] = pb[L];
        r[1] = pb[64 + L];
        r[2] = pb[128 + L];
        r[3] = tb[L];
        if (L < 48) r[4] = tb[64 + L];
    };
    // linear LDS write: lane-contiguous float4 slots, conflict-free
    auto WRITE = [&](int buf, const float4* r) {
        float4* d = &lds[wid][buf][0];
        d[L]       = r[0];
        d[64 + L]  = r[1];
        d[128 + L] = r[2];
        d[192 + L] = r[3];
        if (L < 48) d[256 + L] = r[4];
    };
    // per-cell readback + loss: lane L owns cell t*64+L
    auto COMPUTE = [&](int buf, int t) {
        const float* f = reinterpret_cast<const float*>(&lds[wid][buf][0]);
        const float* pc = f + 12 * L;          // 48 B stride -> b128 x3, 2-way (~free)
        float4 v0 = *reinterpret_cast<const float4*>(pc);
        float4 v1 = *reinterpret_cast<const float4*>(pc + 4);
        float4 v2 = *reinterpret_cast<const float4*>(pc + 8);
        float p[12] = { v0.x, v0.y, v0.z, v0.w, v1.x, v1.y, v1.z, v1.w,
                        v2.x, v2.y, v2.z, v2.w };
        const float* tc = f + 768 + 7 * L;     // 28 B stride -> b32 x7, conflict-free
        float tg[7] = { tc[0], tc[1], tc[2], tc[3], tc[4], tc[5], tc[6] };
        int cell = t * 64 + L;
        int j = cell % S;
        int i = (cell / S) % S;
        acc += cell_loss(p, tg, (float)j, (float)i);
    };

    // software pipeline over 4 tiles: regs + LDS double-buffered, no barriers
    LOADG(A, tile0 + 0);
    LOADG(B, tile0 + 1);

    WRITE(0, A); LOADG(A, tile0 + 2); COMPUTE(0, tile0 + 0);
    WRITE(1, B); LOADG(B, tile0 + 3); COMPUTE(1, tile0 + 1);
    WRITE(0, A);                      COMPUTE(0, tile0 + 2);
    WRITE(1, B);                      COMPUTE(1, tile0 + 3);

    // per-wave reduction in double -> one plain 8B store per wave
    double v = (double)acc;
    #pragma unroll
    for (int off = 32; off > 0; off >>= 1)
        v += __shfl_down(v, off, 64);

    if (L == 0)
        ws[gw] = v;
}

__global__ __launch_bounds__(256)
void reduce_kernel(const double* __restrict__ ws, float* __restrict__ out) {
    int t = threadIdx.x;
    double s = 0.0;
    for (int idx = t; idx < NWAVES; idx += 256) s += ws[idx];

    #pragma unroll
    for (int off = 32; off > 0; off >>= 1)
        s += __shfl_down(s, off, 64);

    __shared__ double sm[4];
    int lane = t & 63, wid = t >> 6;
    if (lane == 0) sm[wid] = s;
    __syncthreads();
    if (t == 0) out[0] = (float)(sm[0] + sm[1] + sm[2] + sm[3]);
}

extern "C" void kernel_launch(void* const* d_in, const int* in_sizes, int n_in,
                              void* d_out, int out_size, void* d_ws, size_t ws_size,
                              hipStream_t stream) {
    const float* pred = (const float*)d_in[0];
    const float* targ = (const float*)d_in[1];
    float* out = (float*)d_out;
    double* ws = (double*)d_ws;

    yolo_loss_kernel<<<NBLK, TPB, 0, stream>>>(pred, targ, ws);
    reduce_kernel<<<1, 256, 0, stream>>>(ws, out);
}